// Round 11
// baseline (520.781 us; speedup 1.0000x reference)
//
#include <hip/hip_runtime.h>
#include <math.h>

typedef __bf16 bf16;
typedef __bf16 bf16x4 __attribute__((ext_vector_type(4)));
typedef __bf16 bf16x8 __attribute__((ext_vector_type(8)));
typedef float floatx4 __attribute__((ext_vector_type(4)));

#define BB 2
#define NN 2048
#define DD 512
#define HH 8
#define HD 64
#define RR 64
#define D3 1536
#define NEG_BIG (-1e30f)
#define TQ 32
#define TBAND 160
#define GRID 512

// async global->LDS, 16B per lane; LDS dest must be wave-uniform base + lane*16
#define GL2LDS16(g, l)                                                        \
    __builtin_amdgcn_global_load_lds(                                         \
        (const __attribute__((address_space(1))) void*)(const void*)(g),      \
        (__attribute__((address_space(3))) void*)(void*)(l), 16, 0, 0)

struct MegaParams {
    const float *nodes, *ln1_g, *ln1_b, *qkv_b, *proj_b, *rep_s, *rel_b,
                *ln2_g, *ln2_b, *mlp_b1, *mlp_b2;
    const float *qkv_w, *proj_w, *mlp_w1, *mlp_w2;
    bf16 *wqt, *wpt, *w1t, *w2t, *x, *qkvb, *vt_g, *y, *hgl, *upd;
    float *invn, *corr_g, *mid, *outf;
    int *cnt;
};

// LDS overlay across phases (max member = attn, 66048 B -> 2 blocks/CU)
union SMem {
    struct { bf16 Ts[64][72]; } t;                       // cvt / vtrans
    struct { float sbuf[4]; } ln;
    struct { bf16 As[2][4096], Bs[2][4096]; } g;         // gemm (32 KB)
    struct { bf16 Xc[TBAND * 72]; float invb[TBAND]; } c;
    struct {
        bf16 Qs[TQ * 136], Ks[TBAND * 72], Vt[64 * 168], Ps[TQ * 168];
        float relb[2][192], rmax2[TQ][2], rsum2[TQ][2];
    } a;                                                  // 66048 B
};

// ------------------------------------------------------------- grid barrier
static __device__ __forceinline__ void grid_barrier(int* cnt, int target) {
    __syncthreads();                       // all block work done (incl vmcnt)
    if (threadIdx.x == 0) {
        __threadfence();                   // release: flush to coherence point
        atomicAdd(cnt, 1);
        while (atomicAdd(cnt, 0) < target) __builtin_amdgcn_s_sleep(2);
        __threadfence();                   // acquire: invalidate stale caches
    }
    __syncthreads();
}

// ---------------------------------------------------------------- reductions
static __device__ __forceinline__ float block_reduce_sum256(float v, float* sbuf) {
    const int tid = threadIdx.x;
    #pragma unroll
    for (int o = 32; o > 0; o >>= 1) v += __shfl_xor(v, o, 64);
    __syncthreads();
    if ((tid & 63) == 0) sbuf[tid >> 6] = v;
    __syncthreads();
    return sbuf[0] + sbuf[1] + sbuf[2] + sbuf[3];
}

static __device__ __forceinline__ void ln_row(
    float* sbuf, const float* in, const float* gw, const float* bw,
    bf16* out, float* invnorm, int row, bool want_inv) {
    const int tid = threadIdx.x;
    const int i0 = tid * 2;
    const float* ip = in + (size_t)row * DD;
    float v0 = ip[i0], v1 = ip[i0 + 1];
    float mean = block_reduce_sum256(v0 + v1, sbuf) * (1.f / DD);
    float d0 = v0 - mean, d1 = v1 - mean;
    float var = block_reduce_sum256(d0 * d0 + d1 * d1, sbuf) * (1.f / DD);
    float rs = rsqrtf(var + 1e-5f);
    float x0 = d0 * rs * gw[i0] + bw[i0];
    float x1 = d1 * rs * gw[i0 + 1] + bw[i0 + 1];
    out[(size_t)row * DD + i0] = (bf16)x0;
    out[(size_t)row * DD + i0 + 1] = (bf16)x1;
    if (want_inv) {
        float s2 = block_reduce_sum256(x0 * x0 + x1 * x1, sbuf);
        if (tid == 0) invnorm[row] = 1.f / fmaxf(sqrtf(s2), 1e-12f);
    }
}

// ------------------------------------------------- weight convert+transpose
static __device__ __forceinline__ void cvt_tile(SMem& sm, const MegaParams& P, int item) {
    const int tid = threadIdx.x;
    const float* W; bf16* Wt; int K, N, bx, by;
    if (item < 192)      { W = P.qkv_w;  Wt = P.wqt; K = 512;  N = 1536; bx = item % 24; by = item / 24; }
    else if (item < 256) { item -= 192; W = P.proj_w; Wt = P.wpt; K = 512;  N = 512;  bx = item % 8;  by = item / 8; }
    else if (item < 384) { item -= 256; W = P.mlp_w1; Wt = P.w1t; K = 512;  N = 1024; bx = item % 16; by = item / 16; }
    else                 { item -= 384; W = P.mlp_w2; Wt = P.w2t; K = 1024; N = 512;  bx = item % 8;  by = item / 8; }
    const int n0 = bx * 64, k0 = by * 64;
    #pragma unroll
    for (int i = 0; i < 4; i++) {
        int r = (tid >> 4) + i * 16;
        int c = (tid & 15) * 4;
        floatx4 v = *(const floatx4*)(W + (size_t)(k0 + r) * N + n0 + c);
        #pragma unroll
        for (int e = 0; e < 4; e++) sm.t.Ts[r][c + e] = (bf16)v[e];
    }
    __syncthreads();
    #pragma unroll
    for (int i = 0; i < 4; i++) {
        int n = (tid >> 4) + i * 16;
        int k = (tid & 15) * 4;
        bf16x4 o;
        #pragma unroll
        for (int e = 0; e < 4; e++) o[e] = sm.t.Ts[k + e][n];
        *(bf16x4*)(Wt + (size_t)(n0 + n) * K + k0 + k) = o;
    }
}

// --------------------------------------------------- GEMM tile (B^T input)
template <int MODE>
static __device__ __forceinline__ void gemm_tile(
    SMem& sm, const bf16* A, const bf16* Bt, const float* bias,
    const float* resid, void* out, int N, int K, int bx, int by) {
    __syncthreads();                      // protect union LDS reuse
    const int tid = threadIdx.x;
    const int w = tid >> 6, lane = tid & 63;
    const int lr = lane & 15, lq = lane >> 4;
    const int rowBase = by * 64, colBase = bx * 64;
    const int wm = (w >> 1) * 32, wn = (w & 1) * 32;

    floatx4 acc[2][2];
    #pragma unroll
    for (int i = 0; i < 2; i++)
        #pragma unroll
        for (int j = 0; j < 2; j++) acc[i][j] = (floatx4){0.f, 0.f, 0.f, 0.f};

    auto stage = [&](int buf, int k0) {
        #pragma unroll
        for (int i = 0; i < 2; i++) {
            int g = i * 256 + tid;
            int row = g >> 3, k8 = (g & 7) ^ (row & 7);
            GL2LDS16(A + (size_t)(rowBase + row) * K + k0 + k8 * 8, &sm.g.As[buf][g * 8]);
        }
        #pragma unroll
        for (int i = 0; i < 2; i++) {
            int g = i * 256 + tid;
            int row = g >> 3, k8 = (g & 7) ^ (row & 7);
            GL2LDS16(Bt + (size_t)(colBase + row) * K + k0 + k8 * 8, &sm.g.Bs[buf][g * 8]);
        }
    };

    const int nsteps = K >> 6;
    stage(0, 0);
    for (int s = 0; s < nsteps; s++) {
        __syncthreads();
        if (s + 1 < nsteps) stage((s + 1) & 1, (s + 1) * 64);
        const int buf = s & 1;
        #pragma unroll
        for (int kb = 0; kb < 2; kb++) {
            bf16x8 af[2], bfr[2];
            #pragma unroll
            for (int i = 0; i < 2; i++) {
                int row = wm + i * 16 + lr;
                int g = row * 8 + ((kb * 4 + lq) ^ (row & 7));
                af[i] = *(bf16x8*)&sm.g.As[buf][g * 8];
            }
            #pragma unroll
            for (int j = 0; j < 2; j++) {
                int row = wn + j * 16 + lr;
                int g = row * 8 + ((kb * 4 + lq) ^ (row & 7));
                bfr[j] = *(bf16x8*)&sm.g.Bs[buf][g * 8];
            }
            #pragma unroll
            for (int i = 0; i < 2; i++)
                #pragma unroll
                for (int j = 0; j < 2; j++)
                    acc[i][j] = __builtin_amdgcn_mfma_f32_16x16x32_bf16(
                        af[i], bfr[j], acc[i][j], 0, 0, 0);
        }
    }

    #pragma unroll
    for (int i = 0; i < 2; i++) {
        #pragma unroll
        for (int j = 0; j < 2; j++) {
            #pragma unroll
            for (int r = 0; r < 4; r++) {
                int row = rowBase + wm + i * 16 + lq * 4 + r;
                int col = colBase + wn + j * 16 + lr;
                size_t idx = (size_t)row * N + col;
                float v = acc[i][j][r] + bias[col];
                if (MODE == 0) {
                    ((bf16*)out)[idx] = (bf16)v;
                } else if (MODE == 1) {
                    ((float*)out)[idx] = v + resid[idx];
                } else if (MODE == 2) {
                    float g = 0.5f * v * (1.f + erff(v * 0.70710678118654752f));
                    ((bf16*)out)[idx] = (bf16)g;
                } else {
                    ((float*)out)[idx] = v + resid[idx];
                }
            }
        }
    }
}

// ------------------------------------------------------------- corr tile
static __device__ __forceinline__ void corr_tile(SMem& sm, const MegaParams& P, int item) {
    const int tid = threadIdx.x;
    const int b = item & 1, n0 = (item >> 1) * TQ;
    const int bN = b * NN;
    const int w = tid >> 6, lane = tid & 63;
    const int lr = lane & 15, lq = lane >> 4;
    const int rowHalf = (w >> 1) * 16, colBase = (w & 1) * 80;

    if (tid < TBAND) {
        int mc = min(max(n0 - RR + tid, 0), NN - 1);
        sm.c.invb[tid] = P.invn[bN + mc];
    }

    floatx4 cacc[5];
    #pragma unroll
    for (int t = 0; t < 5; t++) cacc[t] = (floatx4){0.f, 0.f, 0.f, 0.f};

    for (int c = 0; c < 8; c++) {
        __syncthreads();
        #pragma unroll
        for (int rr = 0; rr < 6; rr++) {
            int G = rr * 256 + tid;
            if (G < 1440) {
                int j = G / 9, gc = G % 9;
                int gcs = min(gc, 7);
                int mc = min(max(n0 - RR + j, 0), NN - 1);
                GL2LDS16(P.x + (size_t)(bN + mc) * DD + c * 64 + gcs * 8, sm.c.Xc + G * 8);
            }
        }
        __syncthreads();
        #pragma unroll
        for (int kb = 0; kb < 2; kb++) {
            bf16x8 a = *(bf16x8*)&sm.c.Xc[(64 + rowHalf + lr) * 72 + kb * 32 + lq * 8];
            #pragma unroll
            for (int t = 0; t < 5; t++) {
                bf16x8 bb = *(bf16x8*)&sm.c.Xc[(colBase + t * 16 + lr) * 72 + kb * 32 + lq * 8];
                cacc[t] = __builtin_amdgcn_mfma_f32_16x16x32_bf16(a, bb, cacc[t], 0, 0, 0);
            }
        }
    }

    float invq[4];
    #pragma unroll
    for (int r = 0; r < 4; r++) invq[r] = sm.c.invb[64 + rowHalf + lq * 4 + r];
    const size_t cbase = (size_t)item * TQ * TBAND;
    #pragma unroll
    for (int t = 0; t < 5; t++) {
        float invk = sm.c.invb[colBase + t * 16 + lr];
        #pragma unroll
        for (int r = 0; r < 4; r++)
            P.corr_g[cbase + (size_t)(rowHalf + lq * 4 + r) * TBAND + colBase + t * 16 + lr] =
                cacc[t][r] * invq[r] * invk;
    }
}

// --------------------------------------------------------- V transpose tile
static __device__ __forceinline__ void vtrans_tile(SMem& sm, const MegaParams& P, int item) {
    const int tid = threadIdx.x;
    const int r0 = (item & 63) * 64;
    const int h = item >> 6;
    #pragma unroll
    for (int i = 0; i < 2; i++) {
        int r = (tid >> 3) + i * 32, c8 = tid & 7;
        *(bf16x8*)&sm.t.Ts[r][c8 * 8] =
            *(const bf16x8*)(P.qkvb + (size_t)(r0 + r) * D3 + 2 * DD + h * HD + c8 * 8);
    }
    __syncthreads();
    #pragma unroll
    for (int i = 0; i < 2; i++) {
        int d = (tid >> 3) + i * 32, c8 = (tid & 7) * 8;
        bf16x8 o;
        #pragma unroll
        for (int e = 0; e < 8; e++) o[e] = sm.t.Ts[c8 + e][d];
        *(bf16x8*)(P.vt_g + (((size_t)(h * HD + d)) << 12) + r0 + c8) = o;
    }
}

// ---------------------------------------------------------------- attention
// item = 512: b(2) x head-pair(4) x n0(64).  2 heads per item.
static __device__ __forceinline__ void attn_item(SMem& sm, const MegaParams& P, int item) {
    const int tid = threadIdx.x;
    const int b = item & 1;
    const int h0 = ((item >> 1) & 3) * 2;
    const int n0 = (item >> 3) * TQ;
    const int bN = b * NN;
    const int w = tid >> 6, lane = tid & 63;
    const int lr = lane & 15, lq = lane >> 4;
    const int rowHalf = (w >> 1) * 16;
    const int colBase = (w & 1) * 80;
    const int c2 = (w & 1) * 32;

    for (int idx = tid; idx < 2 * 191; idx += 256) {
        int hh = idx / 191, dh = idx - hh * 191;
        sm.a.relb[hh][dh] = P.rel_b[(size_t)(dh + (NN - 1 - 95)) * HH + h0 + hh];
    }

    float corrv[5][4];
    {
        const size_t cbase = (size_t)((((item >> 3)) << 1) | b) * TQ * TBAND;
        #pragma unroll
        for (int t = 0; t < 5; t++)
            #pragma unroll
            for (int r = 0; r < 4; r++)
                corrv[t][r] = P.corr_g[cbase + (size_t)(rowHalf + lq * 4 + r) * TBAND +
                                       colBase + t * 16 + lr];
    }

    // stage Q (2 heads): 32 rows x 17 granules = 544
    #pragma unroll
    for (int rr = 0; rr < 3; rr++) {
        int G = rr * 256 + tid;
        if (G < 544) {
            int q = G / 17, gc = G % 17;
            int gcs = min(gc, 15);
            GL2LDS16(P.qkvb + (size_t)(bN + n0 + q) * D3 + h0 * HD + gcs * 8, sm.a.Qs + G * 8);
        }
    }

    for (int h = h0; h < h0 + 2; h++) {
        __syncthreads();
        #pragma unroll
        for (int rr = 0; rr < 6; rr++) {          // K: 160 x 9 granules
            int G = rr * 256 + tid;
            if (G < 1440) {
                int j = G / 9, gc = G % 9;
                int gcs = min(gc, 7);
                int mc = min(max(n0 - RR + j, 0), NN - 1);
                GL2LDS16(P.qkvb + (size_t)(bN + mc) * D3 + DD + h * HD + gcs * 8, sm.a.Ks + G * 8);
            }
        }
        #pragma unroll
        for (int rr = 0; rr < 6; rr++) {          // V^T: 64 x 21 granules
            int G = rr * 256 + tid;
            if (G < 1344) {
                int d = G / 21, gc = G % 21;
                int nsrc = min(max(n0 - RR + gc * 8, 0), NN - 8);
                GL2LDS16(P.vt_g + (((size_t)(h * HD + d)) << 12) + bN + nsrc, sm.a.Vt + G * 8);
            }
        }
        __syncthreads();

        floatx4 sacc[5];
        #pragma unroll
        for (int t = 0; t < 5; t++) sacc[t] = (floatx4){0.f, 0.f, 0.f, 0.f};
        #pragma unroll
        for (int kb = 0; kb < 2; kb++) {
            bf16x8 a = *(bf16x8*)&sm.a.Qs[(rowHalf + lr) * 136 + (h - h0) * 64 + kb * 32 + lq * 8];
            #pragma unroll
            for (int t = 0; t < 5; t++) {
                bf16x8 bb = *(bf16x8*)&sm.a.Ks[(colBase + t * 16 + lr) * 72 + kb * 32 + lq * 8];
                sacc[t] = __builtin_amdgcn_mfma_f32_16x16x32_bf16(a, bb, sacc[t], 0, 0, 0);
            }
        }

        const float srep = P.rep_s[h];
        float l[5][4];
        float mx[4] = {NEG_BIG, NEG_BIG, NEG_BIG, NEG_BIG};
        #pragma unroll
        for (int t = 0; t < 5; t++) {
            int j = colBase + t * 16 + lr;
            int m = n0 - RR + j;
            #pragma unroll
            for (int r = 0; r < 4; r++) {
                int qi = rowHalf + lq * 4 + r;
                int relidx = qi + RR - j;
                bool valid = (relidx >= -RR) && (relidx <= RR) && (m >= 0) && (m < NN);
                float lv = sacc[t][r] * 0.125f + corrv[t][r] * srep +
                           sm.a.relb[h - h0][relidx + 95];
                l[t][r] = valid ? lv : NEG_BIG;
                mx[r] = fmaxf(mx[r], l[t][r]);
            }
        }
        #pragma unroll
        for (int r = 0; r < 4; r++)
            #pragma unroll
            for (int mk = 1; mk <= 8; mk <<= 1)
                mx[r] = fmaxf(mx[r], __shfl_xor(mx[r], mk, 64));
        if (lr == 0) {
            #pragma unroll
            for (int r = 0; r < 4; r++) sm.a.rmax2[rowHalf + lq * 4 + r][w & 1] = mx[r];
        }
        __syncthreads();

        float rm[4], sme[4];
        #pragma unroll
        for (int r = 0; r < 4; r++) {
            int row = rowHalf + lq * 4 + r;
            rm[r] = fmaxf(sm.a.rmax2[row][0], sm.a.rmax2[row][1]);
            sme[r] = 0.f;
        }
        #pragma unroll
        for (int t = 0; t < 5; t++) {
            int j = colBase + t * 16 + lr;
            #pragma unroll
            for (int r = 0; r < 4; r++) {
                float pv = __expf(l[t][r] - rm[r]);
                sme[r] += pv;
                sm.a.Ps[(rowHalf + lq * 4 + r) * 168 + j] = (bf16)pv;
            }
        }
        #pragma unroll
        for (int r = 0; r < 4; r++)
            #pragma unroll
            for (int mk = 1; mk <= 8; mk <<= 1)
                sme[r] += __shfl_xor(sme[r], mk, 64);
        if (lr == 0) {
            #pragma unroll
            for (int r = 0; r < 4; r++) sm.a.rsum2[rowHalf + lq * 4 + r][w & 1] = sme[r];
        }
        __syncthreads();

        floatx4 oacc[2] = {(floatx4){0.f, 0.f, 0.f, 0.f}, (floatx4){0.f, 0.f, 0.f, 0.f}};
        #pragma unroll
        for (int kb = 0; kb < 5; kb++) {
            bf16x8 a = *(bf16x8*)&sm.a.Ps[(rowHalf + lr) * 168 + kb * 32 + lq * 8];
            #pragma unroll
            for (int tt = 0; tt < 2; tt++) {
                bf16x8 bb = *(bf16x8*)&sm.a.Vt[(c2 + tt * 16 + lr) * 168 + kb * 32 + lq * 8];
                oacc[tt] = __builtin_amdgcn_mfma_f32_16x16x32_bf16(a, bb, oacc[tt], 0, 0, 0);
            }
        }
        #pragma unroll
        for (int r = 0; r < 4; r++) {
            int row = rowHalf + lq * 4 + r;
            float rinv = 1.f / (sm.a.rsum2[row][0] + sm.a.rsum2[row][1]);
            #pragma unroll
            for (int tt = 0; tt < 2; tt++) {
                P.upd[(size_t)(bN + n0 + row) * DD + h * HD + c2 + tt * 16 + lr] =
                    (bf16)(oacc[tt][r] * rinv);
            }
        }
    }
}

// ---------------------------------------------------------------- mega kernel
__global__ __launch_bounds__(256, 2) void mega_kernel(MegaParams P) {
    __shared__ SMem sm;
    const int bid = blockIdx.x;

    // P0: weight cvt (512 tiles) + ln1 (8 rows/block)
    cvt_tile(sm, P, bid);
    __syncthreads();
    for (int r = 0; r < 8; r++)
        ln_row(sm.ln.sbuf, P.nodes, P.ln1_g, P.ln1_b, P.x, P.invn, bid * 8 + r, true);
    grid_barrier(P.cnt, GRID * 1);

    // P1: corr (128) + qkv gemm (1536) co-scheduled
    for (int it = bid; it < 1664; it += GRID) {
        __syncthreads();
        if (it < 128)
            corr_tile(sm, P, it);
        else
            gemm_tile<0>(sm, P.x, P.wqt, P.qkv_b, nullptr, P.qkvb, D3, DD,
                         (it - 128) % 24, (it - 128) / 24);
    }
    grid_barrier(P.cnt, GRID * 2);

    // P2: V transpose (512 tiles)
    vtrans_tile(sm, P, bid);
    grid_barrier(P.cnt, GRID * 3);

    // P3: attention (512 items, 2 heads each)
    attn_item(sm, P, bid);
    grid_barrier(P.cnt, GRID * 4);

    // P4: proj gemm + residual (512 tiles)
    gemm_tile<1>(sm, P.upd, P.wpt, P.proj_b, P.nodes, P.mid, DD, DD,
                 bid % 8, bid / 8);
    grid_barrier(P.cnt, GRID * 5);

    // P5: ln2 (8 rows/block)
    for (int r = 0; r < 8; r++)
        ln_row(sm.ln.sbuf, P.mid, P.ln2_g, P.ln2_b, P.y, nullptr, bid * 8 + r, false);
    grid_barrier(P.cnt, GRID * 6);

    // P6: mlp1 gemm + gelu (1024 tiles)
    for (int it = bid; it < 1024; it += GRID)
        gemm_tile<2>(sm, P.y, P.w1t, P.mlp_b1, nullptr, P.hgl, 2 * DD, DD,
                     it % 16, it / 16);
    grid_barrier(P.cnt, GRID * 7);

    // P7: mlp2 gemm + residual -> f32 out
    gemm_tile<3>(sm, P.hgl, P.w2t, P.mlp_b2, P.mid, P.outf, DD, 2 * DD,
                 bid % 8, bid / 8);
}

// ---------------------------------------------------------------- launch
// Inputs FLOAT32; OUTPUT FLOAT32.  Single persistent kernel, 7 grid barriers.
extern "C" void kernel_launch(void* const* d_in, const int* in_sizes, int n_in,
                              void* d_out, int out_size, void* d_ws,
                              size_t ws_size, hipStream_t stream) {
    MegaParams P;
    P.nodes  = (const float*)d_in[0];
    P.ln1_g  = (const float*)d_in[1];
    P.ln1_b  = (const float*)d_in[2];
    P.qkv_w  = (const float*)d_in[3];
    P.qkv_b  = (const float*)d_in[4];
    P.proj_w = (const float*)d_in[5];
    P.proj_b = (const float*)d_in[6];
    P.rep_s  = (const float*)d_in[7];
    P.rel_b  = (const float*)d_in[8];
    P.ln2_g  = (const float*)d_in[9];
    P.ln2_b  = (const float*)d_in[10];
    P.mlp_w1 = (const float*)d_in[11];
    P.mlp_b1 = (const float*)d_in[12];
    P.mlp_w2 = (const float*)d_in[13];
    P.mlp_b2 = (const float*)d_in[14];

    char* p = (char*)d_ws;
    P.invn   = (float*)p;                       // 16 KiB used
    P.cnt    = (int*)(p + (256 << 10));         // barrier counter
    p += (size_t)1 << 20;
    P.wqt    = (bf16*)p;  p += (size_t)DD * D3 * 2;
    P.wpt    = (bf16*)p;  p += (size_t)DD * DD * 2;
    P.w1t    = (bf16*)p;  p += (size_t)DD * 2 * DD * 2;
    P.w2t    = (bf16*)p;  p += (size_t)2 * DD * DD * 2;
    P.x      = (bf16*)p;  p += (size_t)BB * NN * DD * 2;
    P.qkvb   = (bf16*)p;  p += (size_t)BB * NN * D3 * 2;
    char* regA = p;       p += (size_t)BB * NN * DD * 4;   // 8 MiB overlay
    P.corr_g = (float*)regA;                               // 2.62 MiB
    P.vt_g   = (bf16*)(regA + (size_t)BB * (NN / TQ) * TQ * TBAND * 4);  // 4 MiB
    P.mid    = (float*)regA;        // written P4, after attn consumed overlays
    P.y      = P.x;                 // x dead after P1
    P.hgl    = P.qkvb;              // qkvb dead after P3
    P.upd    = (bf16*)d_out;        // consumed by P4; d_out rewritten f32 in P7
    P.outf   = (float*)d_out;

    hipMemsetAsync(P.cnt, 0, 64, stream);
    mega_kernel<<<GRID, 256, 0, stream>>>(P);
}

// Round 12
// 518.911 us; speedup vs baseline: 1.0036x; 1.0036x over previous
//
#include <hip/hip_runtime.h>
#include <math.h>

typedef __bf16 bf16;
typedef __bf16 bf16x4 __attribute__((ext_vector_type(4)));
typedef __bf16 bf16x8 __attribute__((ext_vector_type(8)));
typedef float floatx4 __attribute__((ext_vector_type(4)));

#define BB 2
#define NN 2048
#define DD 512
#define HH 8
#define HD 64
#define RR 64
#define D3 1536
#define NEG_BIG (-1e30f)
#define TQ 32
#define TBAND 160
#define GRID 512

// async global->LDS, 16B per lane; LDS dest must be wave-uniform base + lane*16
#define GL2LDS16(g, l)                                                        \
    __builtin_amdgcn_global_load_lds(                                         \
        (const __attribute__((address_space(1))) void*)(const void*)(g),      \
        (__attribute__((address_space(3))) void*)(void*)(l), 16, 0, 0)

struct MegaParams {
    const float *nodes, *ln1_g, *ln1_b, *qkv_b, *proj_b, *rep_s, *rel_b,
                *ln2_g, *ln2_b, *mlp_b1, *mlp_b2;
    const float *qkv_w, *proj_w, *mlp_w1, *mlp_w2;
    bf16 *wqt, *wpt, *w1t, *w2t, *x, *qkvb, *vt_g, *y, *hgl, *upd;
    float *invn, *corr_g, *mid, *outf;
    int *cnt;
};

// LDS overlay across phases (max member = attn, 66048 B -> 2 blocks/CU)
union SMem {
    struct { bf16 Ts[64][72]; } t;                       // cvt / vtrans
    struct { float sbuf[4]; } ln;
    struct { bf16 As[2][4096], Bs[2][4096]; } g;         // gemm (32 KB)
    struct { bf16 Xc[TBAND * 72]; float invb[TBAND]; } c;
    struct {
        bf16 Qs[TQ * 136], Ks[TBAND * 72], Vt[64 * 168], Ps[TQ * 168];
        float relb[2][192], rmax2[TQ][2], rsum2[TQ][2];
    } a;                                                  // 66048 B
};

// ------------------------------------------------------------- grid barrier
// Arrival: one atomicAdd per block (cheap).  Spin: atomic LOAD (no RMW — reads
// don't serialize at the coherence point) + ~0.85us s_sleep backoff.  The R11
// version spun with atomicAdd(cnt,0): 512 same-address RMWs serialize, queueing
// tens of us per barrier (MfmaUtil 1.7%, all pipes idle — the 440us was spin).
static __device__ __forceinline__ void grid_barrier(int* cnt, int target) {
    __syncthreads();                       // all block work done (incl vmcnt)
    if (threadIdx.x == 0) {
        __threadfence();                   // release: flush to coherence point
        atomicAdd(cnt, 1);
        while (__hip_atomic_load(cnt, __ATOMIC_RELAXED,
                                 __HIP_MEMORY_SCOPE_AGENT) < target)
            __builtin_amdgcn_s_sleep(32);
        __threadfence();                   // acquire: discard stale caches
    }
    __syncthreads();
}

// ---------------------------------------------------------------- reductions
static __device__ __forceinline__ float block_reduce_sum256(float v, float* sbuf) {
    const int tid = threadIdx.x;
    #pragma unroll
    for (int o = 32; o > 0; o >>= 1) v += __shfl_xor(v, o, 64);
    __syncthreads();
    if ((tid & 63) == 0) sbuf[tid >> 6] = v;
    __syncthreads();
    return sbuf[0] + sbuf[1] + sbuf[2] + sbuf[3];
}

static __device__ __forceinline__ void ln_row(
    float* sbuf, const float* in, const float* gw, const float* bw,
    bf16* out, float* invnorm, int row, bool want_inv) {
    const int tid = threadIdx.x;
    const int i0 = tid * 2;
    const float* ip = in + (size_t)row * DD;
    float v0 = ip[i0], v1 = ip[i0 + 1];
    float mean = block_reduce_sum256(v0 + v1, sbuf) * (1.f / DD);
    float d0 = v0 - mean, d1 = v1 - mean;
    float var = block_reduce_sum256(d0 * d0 + d1 * d1, sbuf) * (1.f / DD);
    float rs = rsqrtf(var + 1e-5f);
    float x0 = d0 * rs * gw[i0] + bw[i0];
    float x1 = d1 * rs * gw[i0 + 1] + bw[i0 + 1];
    out[(size_t)row * DD + i0] = (bf16)x0;
    out[(size_t)row * DD + i0 + 1] = (bf16)x1;
    if (want_inv) {
        float s2 = block_reduce_sum256(x0 * x0 + x1 * x1, sbuf);
        if (tid == 0) invnorm[row] = 1.f / fmaxf(sqrtf(s2), 1e-12f);
    }
}

// ------------------------------------------------- weight convert+transpose
static __device__ __forceinline__ void cvt_tile(SMem& sm, const MegaParams& P, int item) {
    const int tid = threadIdx.x;
    const float* W; bf16* Wt; int K, N, bx, by;
    if (item < 192)      { W = P.qkv_w;  Wt = P.wqt; K = 512;  N = 1536; bx = item % 24; by = item / 24; }
    else if (item < 256) { item -= 192; W = P.proj_w; Wt = P.wpt; K = 512;  N = 512;  bx = item % 8;  by = item / 8; }
    else if (item < 384) { item -= 256; W = P.mlp_w1; Wt = P.w1t; K = 512;  N = 1024; bx = item % 16; by = item / 16; }
    else                 { item -= 384; W = P.mlp_w2; Wt = P.w2t; K = 1024; N = 512;  bx = item % 8;  by = item / 8; }
    const int n0 = bx * 64, k0 = by * 64;
    #pragma unroll
    for (int i = 0; i < 4; i++) {
        int r = (tid >> 4) + i * 16;
        int c = (tid & 15) * 4;
        floatx4 v = *(const floatx4*)(W + (size_t)(k0 + r) * N + n0 + c);
        #pragma unroll
        for (int e = 0; e < 4; e++) sm.t.Ts[r][c + e] = (bf16)v[e];
    }
    __syncthreads();
    #pragma unroll
    for (int i = 0; i < 4; i++) {
        int n = (tid >> 4) + i * 16;
        int k = (tid & 15) * 4;
        bf16x4 o;
        #pragma unroll
        for (int e = 0; e < 4; e++) o[e] = sm.t.Ts[k + e][n];
        *(bf16x4*)(Wt + (size_t)(n0 + n) * K + k0 + k) = o;
    }
}

// --------------------------------------------------- GEMM tile (B^T input)
template <int MODE>
static __device__ __forceinline__ void gemm_tile(
    SMem& sm, const bf16* A, const bf16* Bt, const float* bias,
    const float* resid, void* out, int N, int K, int bx, int by) {
    __syncthreads();                      // protect union LDS reuse
    const int tid = threadIdx.x;
    const int w = tid >> 6, lane = tid & 63;
    const int lr = lane & 15, lq = lane >> 4;
    const int rowBase = by * 64, colBase = bx * 64;
    const int wm = (w >> 1) * 32, wn = (w & 1) * 32;

    floatx4 acc[2][2];
    #pragma unroll
    for (int i = 0; i < 2; i++)
        #pragma unroll
        for (int j = 0; j < 2; j++) acc[i][j] = (floatx4){0.f, 0.f, 0.f, 0.f};

    auto stage = [&](int buf, int k0) {
        #pragma unroll
        for (int i = 0; i < 2; i++) {
            int g = i * 256 + tid;
            int row = g >> 3, k8 = (g & 7) ^ (row & 7);
            GL2LDS16(A + (size_t)(rowBase + row) * K + k0 + k8 * 8, &sm.g.As[buf][g * 8]);
        }
        #pragma unroll
        for (int i = 0; i < 2; i++) {
            int g = i * 256 + tid;
            int row = g >> 3, k8 = (g & 7) ^ (row & 7);
            GL2LDS16(Bt + (size_t)(colBase + row) * K + k0 + k8 * 8, &sm.g.Bs[buf][g * 8]);
        }
    };

    const int nsteps = K >> 6;
    stage(0, 0);
    for (int s = 0; s < nsteps; s++) {
        __syncthreads();
        if (s + 1 < nsteps) stage((s + 1) & 1, (s + 1) * 64);
        const int buf = s & 1;
        #pragma unroll
        for (int kb = 0; kb < 2; kb++) {
            bf16x8 af[2], bfr[2];
            #pragma unroll
            for (int i = 0; i < 2; i++) {
                int row = wm + i * 16 + lr;
                int g = row * 8 + ((kb * 4 + lq) ^ (row & 7));
                af[i] = *(bf16x8*)&sm.g.As[buf][g * 8];
            }
            #pragma unroll
            for (int j = 0; j < 2; j++) {
                int row = wn + j * 16 + lr;
                int g = row * 8 + ((kb * 4 + lq) ^ (row & 7));
                bfr[j] = *(bf16x8*)&sm.g.Bs[buf][g * 8];
            }
            #pragma unroll
            for (int i = 0; i < 2; i++)
                #pragma unroll
                for (int j = 0; j < 2; j++)
                    acc[i][j] = __builtin_amdgcn_mfma_f32_16x16x32_bf16(
                        af[i], bfr[j], acc[i][j], 0, 0, 0);
        }
    }

    #pragma unroll
    for (int i = 0; i < 2; i++) {
        #pragma unroll
        for (int j = 0; j < 2; j++) {
            #pragma unroll
            for (int r = 0; r < 4; r++) {
                int row = rowBase + wm + i * 16 + lq * 4 + r;
                int col = colBase + wn + j * 16 + lr;
                size_t idx = (size_t)row * N + col;
                float v = acc[i][j][r] + bias[col];
                if (MODE == 0) {
                    ((bf16*)out)[idx] = (bf16)v;
                } else if (MODE == 1) {
                    ((float*)out)[idx] = v + resid[idx];
                } else if (MODE == 2) {
                    float g = 0.5f * v * (1.f + erff(v * 0.70710678118654752f));
                    ((bf16*)out)[idx] = (bf16)g;
                } else {
                    ((float*)out)[idx] = v + resid[idx];
                }
            }
        }
    }
}

// ------------------------------------------------------------- corr tile
static __device__ __forceinline__ void corr_tile(SMem& sm, const MegaParams& P, int item) {
    const int tid = threadIdx.x;
    const int b = item & 1, n0 = (item >> 1) * TQ;
    const int bN = b * NN;
    const int w = tid >> 6, lane = tid & 63;
    const int lr = lane & 15, lq = lane >> 4;
    const int rowHalf = (w >> 1) * 16, colBase = (w & 1) * 80;

    if (tid < TBAND) {
        int mc = min(max(n0 - RR + tid, 0), NN - 1);
        sm.c.invb[tid] = P.invn[bN + mc];
    }

    floatx4 cacc[5];
    #pragma unroll
    for (int t = 0; t < 5; t++) cacc[t] = (floatx4){0.f, 0.f, 0.f, 0.f};

    for (int c = 0; c < 8; c++) {
        __syncthreads();
        #pragma unroll
        for (int rr = 0; rr < 6; rr++) {
            int G = rr * 256 + tid;
            if (G < 1440) {
                int j = G / 9, gc = G % 9;
                int gcs = min(gc, 7);
                int mc = min(max(n0 - RR + j, 0), NN - 1);
                GL2LDS16(P.x + (size_t)(bN + mc) * DD + c * 64 + gcs * 8, sm.c.Xc + G * 8);
            }
        }
        __syncthreads();
        #pragma unroll
        for (int kb = 0; kb < 2; kb++) {
            bf16x8 a = *(bf16x8*)&sm.c.Xc[(64 + rowHalf + lr) * 72 + kb * 32 + lq * 8];
            #pragma unroll
            for (int t = 0; t < 5; t++) {
                bf16x8 bb = *(bf16x8*)&sm.c.Xc[(colBase + t * 16 + lr) * 72 + kb * 32 + lq * 8];
                cacc[t] = __builtin_amdgcn_mfma_f32_16x16x32_bf16(a, bb, cacc[t], 0, 0, 0);
            }
        }
    }

    float invq[4];
    #pragma unroll
    for (int r = 0; r < 4; r++) invq[r] = sm.c.invb[64 + rowHalf + lq * 4 + r];
    const size_t cbase = (size_t)item * TQ * TBAND;
    #pragma unroll
    for (int t = 0; t < 5; t++) {
        float invk = sm.c.invb[colBase + t * 16 + lr];
        #pragma unroll
        for (int r = 0; r < 4; r++)
            P.corr_g[cbase + (size_t)(rowHalf + lq * 4 + r) * TBAND + colBase + t * 16 + lr] =
                cacc[t][r] * invq[r] * invk;
    }
}

// --------------------------------------------------------- V transpose tile
static __device__ __forceinline__ void vtrans_tile(SMem& sm, const MegaParams& P, int item) {
    const int tid = threadIdx.x;
    const int r0 = (item & 63) * 64;
    const int h = item >> 6;
    #pragma unroll
    for (int i = 0; i < 2; i++) {
        int r = (tid >> 3) + i * 32, c8 = tid & 7;
        *(bf16x8*)&sm.t.Ts[r][c8 * 8] =
            *(const bf16x8*)(P.qkvb + (size_t)(r0 + r) * D3 + 2 * DD + h * HD + c8 * 8);
    }
    __syncthreads();
    #pragma unroll
    for (int i = 0; i < 2; i++) {
        int d = (tid >> 3) + i * 32, c8 = (tid & 7) * 8;
        bf16x8 o;
        #pragma unroll
        for (int e = 0; e < 8; e++) o[e] = sm.t.Ts[c8 + e][d];
        *(bf16x8*)(P.vt_g + (((size_t)(h * HD + d)) << 12) + r0 + c8) = o;
    }
}

// ---------------------------------------------------------------- attention
// item = 512: b(2) x head-pair(4) x n0(64).  2 heads per item.
static __device__ __forceinline__ void attn_item(SMem& sm, const MegaParams& P, int item) {
    const int tid = threadIdx.x;
    const int b = item & 1;
    const int h0 = ((item >> 1) & 3) * 2;
    const int n0 = (item >> 3) * TQ;
    const int bN = b * NN;
    const int w = tid >> 6, lane = tid & 63;
    const int lr = lane & 15, lq = lane >> 4;
    const int rowHalf = (w >> 1) * 16;
    const int colBase = (w & 1) * 80;
    const int c2 = (w & 1) * 32;

    for (int idx = tid; idx < 2 * 191; idx += 256) {
        int hh = idx / 191, dh = idx - hh * 191;
        sm.a.relb[hh][dh] = P.rel_b[(size_t)(dh + (NN - 1 - 95)) * HH + h0 + hh];
    }

    float corrv[5][4];
    {
        const size_t cbase = (size_t)((((item >> 3)) << 1) | b) * TQ * TBAND;
        #pragma unroll
        for (int t = 0; t < 5; t++)
            #pragma unroll
            for (int r = 0; r < 4; r++)
                corrv[t][r] = P.corr_g[cbase + (size_t)(rowHalf + lq * 4 + r) * TBAND +
                                       colBase + t * 16 + lr];
    }

    // stage Q (2 heads): 32 rows x 17 granules = 544
    #pragma unroll
    for (int rr = 0; rr < 3; rr++) {
        int G = rr * 256 + tid;
        if (G < 544) {
            int q = G / 17, gc = G % 17;
            int gcs = min(gc, 15);
            GL2LDS16(P.qkvb + (size_t)(bN + n0 + q) * D3 + h0 * HD + gcs * 8, sm.a.Qs + G * 8);
        }
    }

    for (int h = h0; h < h0 + 2; h++) {
        __syncthreads();
        #pragma unroll
        for (int rr = 0; rr < 6; rr++) {          // K: 160 x 9 granules
            int G = rr * 256 + tid;
            if (G < 1440) {
                int j = G / 9, gc = G % 9;
                int gcs = min(gc, 7);
                int mc = min(max(n0 - RR + j, 0), NN - 1);
                GL2LDS16(P.qkvb + (size_t)(bN + mc) * D3 + DD + h * HD + gcs * 8, sm.a.Ks + G * 8);
            }
        }
        #pragma unroll
        for (int rr = 0; rr < 6; rr++) {          // V^T: 64 x 21 granules
            int G = rr * 256 + tid;
            if (G < 1344) {
                int d = G / 21, gc = G % 21;
                int nsrc = min(max(n0 - RR + gc * 8, 0), NN - 8);
                GL2LDS16(P.vt_g + (((size_t)(h * HD + d)) << 12) + bN + nsrc, sm.a.Vt + G * 8);
            }
        }
        __syncthreads();

        floatx4 sacc[5];
        #pragma unroll
        for (int t = 0; t < 5; t++) sacc[t] = (floatx4){0.f, 0.f, 0.f, 0.f};
        #pragma unroll
        for (int kb = 0; kb < 2; kb++) {
            bf16x8 a = *(bf16x8*)&sm.a.Qs[(rowHalf + lr) * 136 + (h - h0) * 64 + kb * 32 + lq * 8];
            #pragma unroll
            for (int t = 0; t < 5; t++) {
                bf16x8 bb = *(bf16x8*)&sm.a.Ks[(colBase + t * 16 + lr) * 72 + kb * 32 + lq * 8];
                sacc[t] = __builtin_amdgcn_mfma_f32_16x16x32_bf16(a, bb, sacc[t], 0, 0, 0);
            }
        }

        const float srep = P.rep_s[h];
        float l[5][4];
        float mx[4] = {NEG_BIG, NEG_BIG, NEG_BIG, NEG_BIG};
        #pragma unroll
        for (int t = 0; t < 5; t++) {
            int j = colBase + t * 16 + lr;
            int m = n0 - RR + j;
            #pragma unroll
            for (int r = 0; r < 4; r++) {
                int qi = rowHalf + lq * 4 + r;
                int relidx = qi + RR - j;
                bool valid = (relidx >= -RR) && (relidx <= RR) && (m >= 0) && (m < NN);
                float lv = sacc[t][r] * 0.125f + corrv[t][r] * srep +
                           sm.a.relb[h - h0][relidx + 95];
                l[t][r] = valid ? lv : NEG_BIG;
                mx[r] = fmaxf(mx[r], l[t][r]);
            }
        }
        #pragma unroll
        for (int r = 0; r < 4; r++)
            #pragma unroll
            for (int mk = 1; mk <= 8; mk <<= 1)
                mx[r] = fmaxf(mx[r], __shfl_xor(mx[r], mk, 64));
        if (lr == 0) {
            #pragma unroll
            for (int r = 0; r < 4; r++) sm.a.rmax2[rowHalf + lq * 4 + r][w & 1] = mx[r];
        }
        __syncthreads();

        float rm[4], sme[4];
        #pragma unroll
        for (int r = 0; r < 4; r++) {
            int row = rowHalf + lq * 4 + r;
            rm[r] = fmaxf(sm.a.rmax2[row][0], sm.a.rmax2[row][1]);
            sme[r] = 0.f;
        }
        #pragma unroll
        for (int t = 0; t < 5; t++) {
            int j = colBase + t * 16 + lr;
            #pragma unroll
            for (int r = 0; r < 4; r++) {
                float pv = __expf(l[t][r] - rm[r]);
                sme[r] += pv;
                sm.a.Ps[(rowHalf + lq * 4 + r) * 168 + j] = (bf16)pv;
            }
        }
        #pragma unroll
        for (int r = 0; r < 4; r++)
            #pragma unroll
            for (int mk = 1; mk <= 8; mk <<= 1)
                sme[r] += __shfl_xor(sme[r], mk, 64);
        if (lr == 0) {
            #pragma unroll
            for (int r = 0; r < 4; r++) sm.a.rsum2[rowHalf + lq * 4 + r][w & 1] = sme[r];
        }
        __syncthreads();

        floatx4 oacc[2] = {(floatx4){0.f, 0.f, 0.f, 0.f}, (floatx4){0.f, 0.f, 0.f, 0.f}};
        #pragma unroll
        for (int kb = 0; kb < 5; kb++) {
            bf16x8 a = *(bf16x8*)&sm.a.Ps[(rowHalf + lr) * 168 + kb * 32 + lq * 8];
            #pragma unroll
            for (int tt = 0; tt < 2; tt++) {
                bf16x8 bb = *(bf16x8*)&sm.a.Vt[(c2 + tt * 16 + lr) * 168 + kb * 32 + lq * 8];
                oacc[tt] = __builtin_amdgcn_mfma_f32_16x16x32_bf16(a, bb, oacc[tt], 0, 0, 0);
            }
        }
        #pragma unroll
        for (int r = 0; r < 4; r++) {
            int row = rowHalf + lq * 4 + r;
            float rinv = 1.f / (sm.a.rsum2[row][0] + sm.a.rsum2[row][1]);
            #pragma unroll
            for (int tt = 0; tt < 2; tt++) {
                P.upd[(size_t)(bN + n0 + row) * DD + h * HD + c2 + tt * 16 + lr] =
                    (bf16)(oacc[tt][r] * rinv);
            }
        }
    }
}

// ---------------------------------------------------------------- mega kernel
__global__ __launch_bounds__(256, 2) void mega_kernel(MegaParams P) {
    __shared__ SMem sm;
    const int bid = blockIdx.x;

    // P0: weight cvt (512 tiles) + ln1 (8 rows/block)
    cvt_tile(sm, P, bid);
    __syncthreads();
    for (int r = 0; r < 8; r++)
        ln_row(sm.ln.sbuf, P.nodes, P.ln1_g, P.ln1_b, P.x, P.invn, bid * 8 + r, true);
    grid_barrier(P.cnt, GRID * 1);

    // P1: corr (128) + qkv gemm (1536) co-scheduled
    for (int it = bid; it < 1664; it += GRID) {
        __syncthreads();
        if (it < 128)
            corr_tile(sm, P, it);
        else
            gemm_tile<0>(sm, P.x, P.wqt, P.qkv_b, nullptr, P.qkvb, D3, DD,
                         (it - 128) % 24, (it - 128) / 24);
    }
    grid_barrier(P.cnt, GRID * 2);

    // P2: V transpose (512 tiles)
    vtrans_tile(sm, P, bid);
    grid_barrier(P.cnt, GRID * 3);

    // P3: attention (512 items, 2 heads each)
    attn_item(sm, P, bid);
    grid_barrier(P.cnt, GRID * 4);

    // P4: proj gemm + residual (512 tiles)
    gemm_tile<1>(sm, P.upd, P.wpt, P.proj_b, P.nodes, P.mid, DD, DD,
                 bid % 8, bid / 8);
    grid_barrier(P.cnt, GRID * 5);

    // P5: ln2 (8 rows/block)
    for (int r = 0; r < 8; r++)
        ln_row(sm.ln.sbuf, P.mid, P.ln2_g, P.ln2_b, P.y, nullptr, bid * 8 + r, false);
    grid_barrier(P.cnt, GRID * 6);

    // P6: mlp1 gemm + gelu (1024 tiles)
    for (int it = bid; it < 1024; it += GRID)
        gemm_tile<2>(sm, P.y, P.w1t, P.mlp_b1, nullptr, P.hgl, 2 * DD, DD,
                     it % 16, it / 16);
    grid_barrier(P.cnt, GRID * 7);

    // P7: mlp2 gemm + residual -> f32 out
    gemm_tile<3>(sm, P.hgl, P.w2t, P.mlp_b2, P.mid, P.outf, DD, 2 * DD,
                 bid % 8, bid / 8);
}

// ---------------------------------------------------------------- launch
// Inputs FLOAT32; OUTPUT FLOAT32.  Single persistent kernel, 7 grid barriers.
extern "C" void kernel_launch(void* const* d_in, const int* in_sizes, int n_in,
                              void* d_out, int out_size, void* d_ws,
                              size_t ws_size, hipStream_t stream) {
    MegaParams P;
    P.nodes  = (const float*)d_in[0];
    P.ln1_g  = (const float*)d_in[1];
    P.ln1_b  = (const float*)d_in[2];
    P.qkv_w  = (const float*)d_in[3];
    P.qkv_b  = (const float*)d_in[4];
    P.proj_w = (const float*)d_in[5];
    P.proj_b = (const float*)d_in[6];
    P.rep_s  = (const float*)d_in[7];
    P.rel_b  = (const float*)d_in[8];
    P.ln2_g  = (const float*)d_in[9];
    P.ln2_b  = (const float*)d_in[10];
    P.mlp_w1 = (const float*)d_in[11];
    P.mlp_b1 = (const float*)d_in[12];
    P.mlp_w2 = (const float*)d_in[13];
    P.mlp_b2 = (const float*)d_in[14];

    char* p = (char*)d_ws;
    P.invn   = (float*)p;                       // 16 KiB used
    P.cnt    = (int*)(p + (256 << 10));         // barrier counter
    p += (size_t)1 << 20;
    P.wqt    = (bf16*)p;  p += (size_t)DD * D3 * 2;
    P.wpt    = (bf16*)p;  p += (size_t)DD * DD * 2;
    P.w1t    = (bf16*)p;  p += (size_t)DD * 2 * DD * 2;
    P.w2t    = (bf16*)p;  p += (size_t)2 * DD * DD * 2;
    P.x      = (bf16*)p;  p += (size_t)BB * NN * DD * 2;
    P.qkvb   = (bf16*)p;  p += (size_t)BB * NN * D3 * 2;
    char* regA = p;       p += (size_t)BB * NN * DD * 4;   // 8 MiB overlay
    P.corr_g = (float*)regA;                               // 2.62 MiB
    P.vt_g   = (bf16*)(regA + (size_t)BB * (NN / TQ) * TQ * TBAND * 4);  // 4 MiB
    P.mid    = (float*)regA;        // written P4, after attn consumed overlays
    P.y      = P.x;                 // x dead after P1
    P.hgl    = P.qkvb;              // qkvb dead after P3
    P.upd    = (bf16*)d_out;        // consumed by P4; d_out rewritten f32 in P7
    P.outf   = (float*)d_out;

    hipMemsetAsync(P.cnt, 0, 64, stream);
    mega_kernel<<<GRID, 256, 0, stream>>>(P);
}

// Round 13
// 185.650 us; speedup vs baseline: 2.8052x; 2.7951x over previous
//
#include <hip/hip_runtime.h>
#include <math.h>

typedef __bf16 bf16;
typedef __bf16 bf16x4 __attribute__((ext_vector_type(4)));
typedef __bf16 bf16x8 __attribute__((ext_vector_type(8)));
typedef float floatx4 __attribute__((ext_vector_type(4)));

#define BB 2
#define NN 2048
#define DD 512
#define HH 8
#define HD 64
#define RR 64
#define D3 1536
#define NEG_BIG (-1e30f)
#define TQ 32
#define TBAND 160

// async global->LDS, 16B per lane; LDS dest must be wave-uniform base + lane*16
#define GL2LDS16(g, l)                                                        \
    __builtin_amdgcn_global_load_lds(                                         \
        (const __attribute__((address_space(1))) void*)(const void*)(g),      \
        (__attribute__((address_space(3))) void*)(void*)(l), 16, 0, 0)

// ---------------------------------------------------------------- reductions
static __device__ __forceinline__ float block_reduce_sum256(float v, float* sbuf) {
    const int tid = threadIdx.x;
    #pragma unroll
    for (int o = 32; o > 0; o >>= 1) v += __shfl_xor(v, o, 64);
    __syncthreads();
    if ((tid & 63) == 0) sbuf[tid >> 6] = v;
    __syncthreads();
    return sbuf[0] + sbuf[1] + sbuf[2] + sbuf[3];
}

static __device__ __forceinline__ void ln_row(
    float* sbuf, const float* in, const float* gw, const float* bw,
    bf16* out, float* invnorm, int row, bool want_inv) {
    const int tid = threadIdx.x;
    const int i0 = tid * 2;
    const float* ip = in + (size_t)row * DD;
    float v0 = ip[i0], v1 = ip[i0 + 1];
    float mean = block_reduce_sum256(v0 + v1, sbuf) * (1.f / DD);
    float d0 = v0 - mean, d1 = v1 - mean;
    float var = block_reduce_sum256(d0 * d0 + d1 * d1, sbuf) * (1.f / DD);
    float rs = rsqrtf(var + 1e-5f);
    float x0 = d0 * rs * gw[i0] + bw[i0];
    float x1 = d1 * rs * gw[i0 + 1] + bw[i0 + 1];
    out[(size_t)row * DD + i0] = (bf16)x0;
    out[(size_t)row * DD + i0 + 1] = (bf16)x1;
    if (want_inv) {
        float s2 = block_reduce_sum256(x0 * x0 + x1 * x1, sbuf);
        if (tid == 0) invnorm[row] = 1.f / fmaxf(sqrtf(s2), 1e-12f);
    }
}

// ----------------------------------------------- kernel 1: weight cvt + ln1
// grid 1024: bid<512 -> one 64x64 cvt+transpose tile; else 8 LN rows.
union SMemCL {
    bf16 Ts[64][72];
    float sbuf[4];
};
__global__ __launch_bounds__(256) void cvt_ln_kernel(
    const float* __restrict__ qkv_w, const float* __restrict__ proj_w,
    const float* __restrict__ m1w, const float* __restrict__ m2w,
    bf16* __restrict__ wqt, bf16* __restrict__ wpt,
    bf16* __restrict__ w1t, bf16* __restrict__ w2t,
    const float* __restrict__ nodes, const float* __restrict__ ln1_g,
    const float* __restrict__ ln1_b, bf16* __restrict__ x,
    float* __restrict__ invn) {
    __shared__ SMemCL sm;
    const int tid = threadIdx.x;
    int bid = blockIdx.x;
    if (bid >= 512) {                       // LN half
        int r0 = (bid - 512) * 8;
        for (int r = 0; r < 8; r++)
            ln_row(sm.sbuf, nodes, ln1_g, ln1_b, x, invn, r0 + r, true);
        return;
    }
    const float* W; bf16* Wt; int K, N, bx, by;
    if (bid < 192)      { W = qkv_w; Wt = wqt; K = 512;  N = 1536; bx = bid % 24; by = bid / 24; }
    else if (bid < 256) { bid -= 192; W = proj_w; Wt = wpt; K = 512;  N = 512;  bx = bid % 8;  by = bid / 8; }
    else if (bid < 384) { bid -= 256; W = m1w; Wt = w1t; K = 512;  N = 1024; bx = bid % 16; by = bid / 16; }
    else                { bid -= 384; W = m2w; Wt = w2t; K = 1024; N = 512;  bx = bid % 8;  by = bid / 8; }
    const int n0 = bx * 64, k0 = by * 64;
    #pragma unroll
    for (int i = 0; i < 4; i++) {
        int r = (tid >> 4) + i * 16;
        int c = (tid & 15) * 4;
        floatx4 v = *(const floatx4*)(W + (size_t)(k0 + r) * N + n0 + c);
        #pragma unroll
        for (int e = 0; e < 4; e++) sm.Ts[r][c + e] = (bf16)v[e];
    }
    __syncthreads();
    #pragma unroll
    for (int i = 0; i < 4; i++) {
        int n = (tid >> 4) + i * 16;
        int k = (tid & 15) * 4;
        bf16x4 o;
        #pragma unroll
        for (int e = 0; e < 4; e++) o[e] = sm.Ts[k + e][n];
        *(bf16x4*)(Wt + (size_t)(n0 + n) * K + k0 + k) = o;
    }
}

// --------------------------------------- kernel 2: qkv GEMM (+V^T) + corr
// grid 1664: bid<1536 gemm tiles (bx>=16 -> V cols, transpose epilogue to
// vt_g); bid>=1536 -> corr tile (128 items).
union SMemQC {
    struct { bf16 As[2][4096], Bs[2][4096]; } g;          // 32 KB
    struct { bf16 Ts[64][72]; } t;     // aliases g; used only after K-loop+sync
    struct { bf16 Xc[TBAND * 72]; float invb[TBAND]; } c; // 23.7 KB
};
__global__ __launch_bounds__(256) void qkv_corr_kernel(
    const bf16* __restrict__ x, const bf16* __restrict__ wqt,
    const float* __restrict__ qkv_b, const float* __restrict__ invn,
    bf16* __restrict__ qkvb, bf16* __restrict__ vt_g,
    float* __restrict__ corr_g) {
    __shared__ SMemQC sm;
    const int tid = threadIdx.x;
    const int bid = blockIdx.x;
    const int w = tid >> 6, lane = tid & 63;
    const int lr = lane & 15, lq = lane >> 4;

    if (bid >= 1536) {                     // ---- corr tile
        const int item = bid - 1536;
        const int b = item & 1, n0 = (item >> 1) * TQ;
        const int bN = b * NN;
        const int rowHalf = (w >> 1) * 16, colBase = (w & 1) * 80;
        if (tid < TBAND) {
            int mc = min(max(n0 - RR + tid, 0), NN - 1);
            sm.c.invb[tid] = invn[bN + mc];
        }
        floatx4 cacc[5];
        #pragma unroll
        for (int t = 0; t < 5; t++) cacc[t] = (floatx4){0.f, 0.f, 0.f, 0.f};
        for (int c = 0; c < 8; c++) {
            __syncthreads();
            #pragma unroll
            for (int rr = 0; rr < 6; rr++) {
                int G = rr * 256 + tid;
                if (G < 1440) {
                    int j = G / 9, gc = G % 9;
                    int gcs = min(gc, 7);
                    int mc = min(max(n0 - RR + j, 0), NN - 1);
                    GL2LDS16(x + (size_t)(bN + mc) * DD + c * 64 + gcs * 8, sm.c.Xc + G * 8);
                }
            }
            __syncthreads();
            #pragma unroll
            for (int kb = 0; kb < 2; kb++) {
                bf16x8 a = *(bf16x8*)&sm.c.Xc[(64 + rowHalf + lr) * 72 + kb * 32 + lq * 8];
                #pragma unroll
                for (int t = 0; t < 5; t++) {
                    bf16x8 bb = *(bf16x8*)&sm.c.Xc[(colBase + t * 16 + lr) * 72 + kb * 32 + lq * 8];
                    cacc[t] = __builtin_amdgcn_mfma_f32_16x16x32_bf16(a, bb, cacc[t], 0, 0, 0);
                }
            }
        }
        float invq[4];
        #pragma unroll
        for (int r = 0; r < 4; r++) invq[r] = sm.c.invb[64 + rowHalf + lq * 4 + r];
        const size_t cbase = (size_t)item * TQ * TBAND;
        #pragma unroll
        for (int t = 0; t < 5; t++) {
            float invk = sm.c.invb[colBase + t * 16 + lr];
            #pragma unroll
            for (int r = 0; r < 4; r++)
                corr_g[cbase + (size_t)(rowHalf + lq * 4 + r) * TBAND + colBase + t * 16 + lr] =
                    cacc[t][r] * invq[r] * invk;
        }
        return;
    }

    // ---- gemm tile (A = x [4096][512], Bt = wqt [1536][512])
    const int bx = bid % 24, by = bid / 24;
    const int rowBase = by * 64, colBase = bx * 64;
    const int wm = (w >> 1) * 32, wn = (w & 1) * 32;

    floatx4 acc[2][2];
    #pragma unroll
    for (int i = 0; i < 2; i++)
        #pragma unroll
        for (int j = 0; j < 2; j++) acc[i][j] = (floatx4){0.f, 0.f, 0.f, 0.f};

    auto stage = [&](int buf, int k0) {
        #pragma unroll
        for (int i = 0; i < 2; i++) {
            int g = i * 256 + tid;
            int row = g >> 3, k8 = (g & 7) ^ (row & 7);
            GL2LDS16(x + (size_t)(rowBase + row) * DD + k0 + k8 * 8, &sm.g.As[buf][g * 8]);
        }
        #pragma unroll
        for (int i = 0; i < 2; i++) {
            int g = i * 256 + tid;
            int row = g >> 3, k8 = (g & 7) ^ (row & 7);
            GL2LDS16(wqt + (size_t)(colBase + row) * DD + k0 + k8 * 8, &sm.g.Bs[buf][g * 8]);
        }
    };

    stage(0, 0);
    for (int s = 0; s < 8; s++) {
        __syncthreads();
        if (s + 1 < 8) stage((s + 1) & 1, (s + 1) * 64);
        const int buf = s & 1;
        #pragma unroll
        for (int kb = 0; kb < 2; kb++) {
            bf16x8 af[2], bfr[2];
            #pragma unroll
            for (int i = 0; i < 2; i++) {
                int row = wm + i * 16 + lr;
                int g = row * 8 + ((kb * 4 + lq) ^ (row & 7));
                af[i] = *(bf16x8*)&sm.g.As[buf][g * 8];
            }
            #pragma unroll
            for (int j = 0; j < 2; j++) {
                int row = wn + j * 16 + lr;
                int g = row * 8 + ((kb * 4 + lq) ^ (row & 7));
                bfr[j] = *(bf16x8*)&sm.g.Bs[buf][g * 8];
            }
            #pragma unroll
            for (int i = 0; i < 2; i++)
                #pragma unroll
                for (int j = 0; j < 2; j++)
                    acc[i][j] = __builtin_amdgcn_mfma_f32_16x16x32_bf16(
                        af[i], bfr[j], acc[i][j], 0, 0, 0);
        }
    }

    if (bx < 16) {                         // Q/K columns: store to qkvb
        #pragma unroll
        for (int i = 0; i < 2; i++)
            #pragma unroll
            for (int j = 0; j < 2; j++)
                #pragma unroll
                for (int r = 0; r < 4; r++) {
                    int row = rowBase + wm + i * 16 + lq * 4 + r;
                    int col = colBase + wn + j * 16 + lr;
                    qkvb[(size_t)row * D3 + col] = (bf16)(acc[i][j][r] + qkv_b[col]);
                }
    } else {                               // V columns: transpose -> vt_g
        __syncthreads();                   // g.As consumed; reuse as Ts
        #pragma unroll
        for (int i = 0; i < 2; i++)
            #pragma unroll
            for (int j = 0; j < 2; j++)
                #pragma unroll
                for (int r = 0; r < 4; r++) {
                    int nl = wm + i * 16 + lq * 4 + r;
                    int dl = wn + j * 16 + lr;
                    sm.t.Ts[nl][dl] = (bf16)(acc[i][j][r] + qkv_b[colBase + dl]);
                }
        __syncthreads();
        const int dV = colBase - 1024;     // 0..448
        #pragma unroll
        for (int i2 = 0; i2 < 2; i2++) {
            int d = (tid >> 3) + i2 * 32;
            int n8 = (tid & 7) * 8;
            bf16x8 o;
            #pragma unroll
            for (int e = 0; e < 8; e++) o[e] = sm.t.Ts[n8 + e][d];
            *(bf16x8*)(vt_g + (((size_t)(dV + d)) << 12) + rowBase + n8) = o;
        }
    }
}

// --------------------------------------------- GEMM kernels (modes 1,2,3)
//  1: +resid f32->f32 (proj->mid) | 2: gelu->bf16 (mlp1) | 3: +resid ->f32 out
template <int MODE>
__global__ __launch_bounds__(256) void gemm_bt(
    const bf16* __restrict__ A, const bf16* __restrict__ Bt,
    const float* __restrict__ bias, const float* __restrict__ resid,
    void* __restrict__ out, int M, int N, int K) {
    __shared__ __align__(16) bf16 As[2][64 * 64];
    __shared__ __align__(16) bf16 Bs[2][64 * 64];
    const int tid = threadIdx.x;
    const int w = tid >> 6, lane = tid & 63;
    const int lr = lane & 15, lq = lane >> 4;
    const int rowBase = blockIdx.y * 64, colBase = blockIdx.x * 64;
    const int wm = (w >> 1) * 32, wn = (w & 1) * 32;

    floatx4 acc[2][2];
    #pragma unroll
    for (int i = 0; i < 2; i++)
        #pragma unroll
        for (int j = 0; j < 2; j++) acc[i][j] = (floatx4){0.f, 0.f, 0.f, 0.f};

    auto stage = [&](int buf, int k0) {
        #pragma unroll
        for (int i = 0; i < 2; i++) {
            int g = i * 256 + tid;
            int row = g >> 3, k8 = (g & 7) ^ (row & 7);
            GL2LDS16(A + (size_t)(rowBase + row) * K + k0 + k8 * 8, &As[buf][g * 8]);
        }
        #pragma unroll
        for (int i = 0; i < 2; i++) {
            int g = i * 256 + tid;
            int row = g >> 3, k8 = (g & 7) ^ (row & 7);
            GL2LDS16(Bt + (size_t)(colBase + row) * K + k0 + k8 * 8, &Bs[buf][g * 8]);
        }
    };

    const int nsteps = K >> 6;
    stage(0, 0);
    for (int s = 0; s < nsteps; s++) {
        __syncthreads();
        if (s + 1 < nsteps) stage((s + 1) & 1, (s + 1) * 64);
        const int buf = s & 1;
        #pragma unroll
        for (int kb = 0; kb < 2; kb++) {
            bf16x8 af[2], bfr[2];
            #pragma unroll
            for (int i = 0; i < 2; i++) {
                int row = wm + i * 16 + lr;
                int g = row * 8 + ((kb * 4 + lq) ^ (row & 7));
                af[i] = *(bf16x8*)&As[buf][g * 8];
            }
            #pragma unroll
            for (int j = 0; j < 2; j++) {
                int row = wn + j * 16 + lr;
                int g = row * 8 + ((kb * 4 + lq) ^ (row & 7));
                bfr[j] = *(bf16x8*)&Bs[buf][g * 8];
            }
            #pragma unroll
            for (int i = 0; i < 2; i++)
                #pragma unroll
                for (int j = 0; j < 2; j++)
                    acc[i][j] = __builtin_amdgcn_mfma_f32_16x16x32_bf16(
                        af[i], bfr[j], acc[i][j], 0, 0, 0);
        }
    }

    #pragma unroll
    for (int i = 0; i < 2; i++) {
        #pragma unroll
        for (int j = 0; j < 2; j++) {
            #pragma unroll
            for (int r = 0; r < 4; r++) {
                int row = rowBase + wm + i * 16 + lq * 4 + r;
                int col = colBase + wn + j * 16 + lr;
                size_t idx = (size_t)row * N + col;
                float v = acc[i][j][r] + bias[col];
                if (MODE == 1) {
                    ((float*)out)[idx] = v + resid[idx];
                } else if (MODE == 2) {
                    float g = 0.5f * v * (1.f + erff(v * 0.70710678118654752f));
                    ((bf16*)out)[idx] = (bf16)g;
                } else {
                    ((float*)out)[idx] = v + resid[idx];
                }
            }
        }
    }
}

// ---------------------------------------------------------------- LayerNorm2
__global__ __launch_bounds__(256) void ln2_kernel(
    const float* __restrict__ in, const float* __restrict__ gw,
    const float* __restrict__ bw, bf16* __restrict__ out) {
    __shared__ float sbuf[4];
    ln_row(sbuf, in, gw, bw, out, nullptr, blockIdx.x, false);
}

// ---------------------------------------------------------------- attention
// grid 512: b(2) x head-pair(4) x n0(64), 2 heads per block, 2 blocks/CU.
__global__ __launch_bounds__(256) void attn_kernel(
    const bf16* __restrict__ qkv, const bf16* __restrict__ vt_g,
    const float* __restrict__ corr_g, const float* __restrict__ rep_scale,
    const float* __restrict__ rel_bias, bf16* __restrict__ upd) {
    __shared__ __align__(16) bf16 Qs[TQ * 136];
    __shared__ __align__(16) bf16 Ks[TBAND * 72];
    __shared__ __align__(16) bf16 Vt[64 * 168];
    __shared__ __align__(16) bf16 Ps[TQ * 168];
    __shared__ float relb[2][192];
    __shared__ float rmax2[TQ][2];
    __shared__ float rsum2[TQ][2];

    const int tid = threadIdx.x;
    const int item = blockIdx.x;
    const int b = item & 1;
    const int h0 = ((item >> 1) & 3) * 2;
    const int n0 = (item >> 3) * TQ;
    const int bN = b * NN;
    const int w = tid >> 6, lane = tid & 63;
    const int lr = lane & 15, lq = lane >> 4;
    const int rowHalf = (w >> 1) * 16;
    const int colBase = (w & 1) * 80;
    const int c2 = (w & 1) * 32;

    for (int idx = tid; idx < 2 * 191; idx += 256) {
        int hh = idx / 191, dh = idx - hh * 191;
        relb[hh][dh] = rel_bias[(size_t)(dh + (NN - 1 - 95)) * HH + h0 + hh];
    }

    float corrv[5][4];
    {
        const size_t cbase = (size_t)((((item >> 3)) << 1) | b) * TQ * TBAND;
        #pragma unroll
        for (int t = 0; t < 5; t++)
            #pragma unroll
            for (int r = 0; r < 4; r++)
                corrv[t][r] = corr_g[cbase + (size_t)(rowHalf + lq * 4 + r) * TBAND +
                                     colBase + t * 16 + lr];
    }

    // stage Q (2 heads): 32 rows x 17 granules = 544
    #pragma unroll
    for (int rr = 0; rr < 3; rr++) {
        int G = rr * 256 + tid;
        if (G < 544) {
            int q = G / 17, gc = G % 17;
            int gcs = min(gc, 15);
            GL2LDS16(qkv + (size_t)(bN + n0 + q) * D3 + h0 * HD + gcs * 8, Qs + G * 8);
        }
    }

    for (int h = h0; h < h0 + 2; h++) {
        __syncthreads();
        #pragma unroll
        for (int rr = 0; rr < 6; rr++) {          // K: 160 x 9 granules
            int G = rr * 256 + tid;
            if (G < 1440) {
                int j = G / 9, gc = G % 9;
                int gcs = min(gc, 7);
                int mc = min(max(n0 - RR + j, 0), NN - 1);
                GL2LDS16(qkv + (size_t)(bN + mc) * D3 + DD + h * HD + gcs * 8, Ks + G * 8);
            }
        }
        #pragma unroll
        for (int rr = 0; rr < 6; rr++) {          // V^T: 64 x 21 granules
            int G = rr * 256 + tid;
            if (G < 1344) {
                int d = G / 21, gc = G % 21;
                int nsrc = min(max(n0 - RR + gc * 8, 0), NN - 8);
                GL2LDS16(vt_g + (((size_t)(h * HD + d)) << 12) + bN + nsrc, Vt + G * 8);
            }
        }
        __syncthreads();

        floatx4 sacc[5];
        #pragma unroll
        for (int t = 0; t < 5; t++) sacc[t] = (floatx4){0.f, 0.f, 0.f, 0.f};
        #pragma unroll
        for (int kb = 0; kb < 2; kb++) {
            bf16x8 a = *(bf16x8*)&Qs[(rowHalf + lr) * 136 + (h - h0) * 64 + kb * 32 + lq * 8];
            #pragma unroll
            for (int t = 0; t < 5; t++) {
                bf16x8 bb = *(bf16x8*)&Ks[(colBase + t * 16 + lr) * 72 + kb * 32 + lq * 8];
                sacc[t] = __builtin_amdgcn_mfma_f32_16x16x32_bf16(a, bb, sacc[t], 0, 0, 0);
            }
        }

        const float srep = rep_scale[h];
        float l[5][4];
        float mx[4] = {NEG_BIG, NEG_BIG, NEG_BIG, NEG_BIG};
        #pragma unroll
        for (int t = 0; t < 5; t++) {
            int j = colBase + t * 16 + lr;
            int m = n0 - RR + j;
            #pragma unroll
            for (int r = 0; r < 4; r++) {
                int qi = rowHalf + lq * 4 + r;
                int relidx = qi + RR - j;
                bool valid = (relidx >= -RR) && (relidx <= RR) && (m >= 0) && (m < NN);
                float lv = sacc[t][r] * 0.125f + corrv[t][r] * srep +
                           relb[h - h0][relidx + 95];
                l[t][r] = valid ? lv : NEG_BIG;
                mx[r] = fmaxf(mx[r], l[t][r]);
            }
        }
        #pragma unroll
        for (int r = 0; r < 4; r++)
            #pragma unroll
            for (int mk = 1; mk <= 8; mk <<= 1)
                mx[r] = fmaxf(mx[r], __shfl_xor(mx[r], mk, 64));
        if (lr == 0) {
            #pragma unroll
            for (int r = 0; r < 4; r++) rmax2[rowHalf + lq * 4 + r][w & 1] = mx[r];
        }
        __syncthreads();

        float rm[4], sme[4];
        #pragma unroll
        for (int r = 0; r < 4; r++) {
            int row = rowHalf + lq * 4 + r;
            rm[r] = fmaxf(rmax2[row][0], rmax2[row][1]);
            sme[r] = 0.f;
        }
        #pragma unroll
        for (int t = 0; t < 5; t++) {
            int j = colBase + t * 16 + lr;
            #pragma unroll
            for (int r = 0; r < 4; r++) {
                float pv = __expf(l[t][r] - rm[r]);
                sme[r] += pv;
                Ps[(rowHalf + lq * 4 + r) * 168 + j] = (bf16)pv;
            }
        }
        #pragma unroll
        for (int r = 0; r < 4; r++)
            #pragma unroll
            for (int mk = 1; mk <= 8; mk <<= 1)
                sme[r] += __shfl_xor(sme[r], mk, 64);
        if (lr == 0) {
            #pragma unroll
            for (int r = 0; r < 4; r++) rsum2[rowHalf + lq * 4 + r][w & 1] = sme[r];
        }
        __syncthreads();

        floatx4 oacc[2] = {(floatx4){0.f, 0.f, 0.f, 0.f}, (floatx4){0.f, 0.f, 0.f, 0.f}};
        #pragma unroll
        for (int kb = 0; kb < 5; kb++) {
            bf16x8 a = *(bf16x8*)&Ps[(rowHalf + lr) * 168 + kb * 32 + lq * 8];
            #pragma unroll
            for (int tt = 0; tt < 2; tt++) {
                bf16x8 bb = *(bf16x8*)&Vt[(c2 + tt * 16 + lr) * 168 + kb * 32 + lq * 8];
                oacc[tt] = __builtin_amdgcn_mfma_f32_16x16x32_bf16(a, bb, oacc[tt], 0, 0, 0);
            }
        }
        #pragma unroll
        for (int r = 0; r < 4; r++) {
            int row = rowHalf + lq * 4 + r;
            float rinv = 1.f / (rsum2[row][0] + rsum2[row][1]);
            #pragma unroll
            for (int tt = 0; tt < 2; tt++) {
                upd[(size_t)(bN + n0 + row) * DD + h * HD + c2 + tt * 16 + lr] =
                    (bf16)(oacc[tt][r] * rinv);
            }
        }
    }
}

// ---------------------------------------------------------------- launch
// Inputs FLOAT32; OUTPUT FLOAT32.  7 kernels (mega-kernel reverted: measured
// ~55us per device-scope grid barrier on 8-XCD CDNA4 — kernel boundaries are
// cheaper).
extern "C" void kernel_launch(void* const* d_in, const int* in_sizes, int n_in,
                              void* d_out, int out_size, void* d_ws,
                              size_t ws_size, hipStream_t stream) {
    const float* nodes  = (const float*)d_in[0];
    const float* ln1_g  = (const float*)d_in[1];
    const float* ln1_b  = (const float*)d_in[2];
    const float* qkv_w  = (const float*)d_in[3];
    const float* qkv_b  = (const float*)d_in[4];
    const float* proj_w = (const float*)d_in[5];
    const float* proj_b = (const float*)d_in[6];
    const float* rep_s  = (const float*)d_in[7];
    const float* rel_b  = (const float*)d_in[8];
    const float* ln2_g  = (const float*)d_in[9];
    const float* ln2_b  = (const float*)d_in[10];
    const float* mlp_w1 = (const float*)d_in[11];
    const float* mlp_b1 = (const float*)d_in[12];
    const float* mlp_w2 = (const float*)d_in[13];
    const float* mlp_b2 = (const float*)d_in[14];

    char* p = (char*)d_ws;
    float* invn = (float*)p;            p += (size_t)1 << 20;
    bf16*  wqt  = (bf16*)p;             p += (size_t)DD * D3 * 2;
    bf16*  wpt  = (bf16*)p;             p += (size_t)DD * DD * 2;
    bf16*  w1t  = (bf16*)p;             p += (size_t)DD * 2 * DD * 2;
    bf16*  w2t  = (bf16*)p;             p += (size_t)2 * DD * DD * 2;
    bf16*  x    = (bf16*)p;             p += (size_t)BB * NN * DD * 2;
    bf16*  qkvb = (bf16*)p;             p += (size_t)BB * NN * D3 * 2;
    char*  regA = p;                    p += (size_t)BB * NN * DD * 4;   // 8 MiB
    float* corr_g = (float*)regA;                               // 2.62 MiB
    bf16*  vt_g   = (bf16*)(regA + (size_t)BB * (NN / TQ) * TQ * TBAND * 4);  // 4 MiB
    float* mid    = (float*)regA;   // written by proj after attn consumed overlays
    bf16*  y    = x;                // alias: x dead after qkv_corr
    bf16*  hgl  = qkvb;             // alias: qkvb dead after attn
    bf16*  upd  = (bf16*)d_out;     // consumed by proj; d_out rewritten f32 by mlp2

    const int M = BB * NN;  // 4096

    cvt_ln_kernel<<<1024, 256, 0, stream>>>(
        qkv_w, proj_w, mlp_w1, mlp_w2, wqt, wpt, w1t, w2t,
        nodes, ln1_g, ln1_b, x, invn);
    qkv_corr_kernel<<<1664, 256, 0, stream>>>(
        x, wqt, qkv_b, invn, qkvb, vt_g, corr_g);
    attn_kernel<<<512, 256, 0, stream>>>(
        qkvb, vt_g, corr_g, rep_s, rel_b, upd);
    gemm_bt<1><<<dim3(DD / 64, M / 64), 256, 0, stream>>>(
        upd, wpt, proj_b, nodes, mid, M, DD, DD);
    ln2_kernel<<<M, 256, 0, stream>>>(mid, ln2_g, ln2_b, y);
    gemm_bt<2><<<dim3(2 * DD / 64, M / 64), 256, 0, stream>>>(
        y, w1t, mlp_b1, nullptr, hgl, M, 2 * DD, DD);
    gemm_bt<3><<<dim3(DD / 64, M / 64), 256, 0, stream>>>(
        hgl, w2t, mlp_b2, mid, (float*)d_out, M, DD, 2 * DD);
}